// Round 2
// baseline (525.127 us; speedup 1.0000x reference)
//
#include <hip/hip_runtime.h>
#include <cstdint>
#include <cstddef>

#define B_SZ 8
#define N1 4096
#define N2 256
#define LTOT 4352          // N1 + N2
#define DIMD 1024
#define HEADS 16
#define DH 64
#define MKV (B_SZ * LTOT)  // 34816
#define ATILE 64
#define AITERS (LTOT / ATILE)  // 68
#define G0_BLOCKS 4352         // 272 mt x 16 nt
#define MT_PER_XCD 34          // 272 / 8

typedef _Float16 f16;
typedef f16 f16x4_t __attribute__((ext_vector_type(4)));
typedef f16 f16x8_t __attribute__((ext_vector_type(8)));
typedef float f32x4_t __attribute__((ext_vector_type(4)));

// async global -> LDS, 16B per lane. LDS dest is wave-uniform base + lane*16.
__device__ __forceinline__ void g2l16(const void* g, void* l) {
  __builtin_amdgcn_global_load_lds(
      (__attribute__((address_space(1))) void*)g,
      (__attribute__((address_space(3))) void*)l, 16, 0, 0);
}

// ---------------------------------------------------------------------------
// Kernel 1: prep = layernorm/modulation (blocks 0..MKV-1) + weight casts
// ---------------------------------------------------------------------------
__global__ __launch_bounds__(256) void prep_kernel(
    const float* __restrict__ x, const float* __restrict__ lat,
    const float* __restrict__ shift, const float* __restrict__ scale,
    const float* __restrict__ ln1w, const float* __restrict__ ln1b,
    const float* __restrict__ ln2w, const float* __restrict__ ln2b,
    const float* __restrict__ Wq, const float* __restrict__ Wkv,
    const float* __restrict__ Wo, f16* __restrict__ kv_in,
    f16* __restrict__ Wq16, f16* __restrict__ Wkv16, f16* __restrict__ Wo16) {
  const int bid = blockIdx.x;
  const int tid = threadIdx.x;
  if (bid >= MKV) {  // weight casts: 1024 f32 per block
    const int c = bid - MKV;
    const float* src;
    f16* dst;
    int off;
    if (c < 1024) { src = Wq; dst = Wq16; off = c; }
    else if (c < 3072) { src = Wkv; dst = Wkv16; off = c - 1024; }
    else { src = Wo; dst = Wo16; off = c - 3072; }
    const int i = off * 256 + tid;
    float4 v = ((const float4*)src)[i];
    f16x4_t o = {(f16)v.x, (f16)v.y, (f16)v.z, (f16)v.w};
    ((f16x4_t*)dst)[i] = o;
    return;
  }
  const int row = bid;
  const int b = row / LTOT;
  const int n = row - b * LTOT;
  const bool is_lat = (n >= N1);
  const float* src = is_lat ? (lat + (size_t)(b * N2 + (n - N1)) * DIMD)
                            : (x + (size_t)(b * N1 + n) * DIMD);
  float4 v = ((const float4*)src)[tid];
  float s = v.x + v.y + v.z + v.w;
  float s2 = v.x * v.x + v.y * v.y + v.z * v.z + v.w * v.w;
#pragma unroll
  for (int m = 1; m <= 32; m <<= 1) {
    s += __shfl_xor(s, m, 64);
    s2 += __shfl_xor(s2, m, 64);
  }
  __shared__ float red[8];
  const int wave = tid >> 6;
  if ((tid & 63) == 0) { red[wave * 2] = s; red[wave * 2 + 1] = s2; }
  __syncthreads();
  s = red[0] + red[2] + red[4] + red[6];
  s2 = red[1] + red[3] + red[5] + red[7];
  const float mean = s * (1.0f / DIMD);
  const float var = fmaxf(s2 * (1.0f / DIMD) - mean * mean, 0.0f);
  const float rstd = rsqrtf(var + 1e-5f);
  const float4 w4 = ((const float4*)(is_lat ? ln2w : ln1w))[tid];
  const float4 b4 = ((const float4*)(is_lat ? ln2b : ln1b))[tid];
  float y0 = (v.x - mean) * rstd * w4.x + b4.x;
  float y1 = (v.y - mean) * rstd * w4.y + b4.y;
  float y2 = (v.z - mean) * rstd * w4.z + b4.z;
  float y3 = (v.w - mean) * rstd * w4.w + b4.w;
  if (is_lat) {
    float4 sc = ((const float4*)(scale + (size_t)b * DIMD))[tid];
    float4 sh = ((const float4*)(shift + (size_t)b * DIMD))[tid];
    y0 = y0 * (1.0f + sc.x) + sh.x;
    y1 = y1 * (1.0f + sc.y) + sh.y;
    y2 = y2 * (1.0f + sc.z) + sh.z;
    y3 = y3 * (1.0f + sc.w) + sh.w;
  }
  f16x4_t o = {(f16)y0, (f16)y1, (f16)y2, (f16)y3};
  *(f16x4_t*)(kv_in + (size_t)row * DIMD + tid * 4) = o;
}

// ---------------------------------------------------------------------------
// Kernel 2: fused pre-attention GEMMs (kv + q) in ONE dispatch.
// 128x128 tiles, BK=32, 16x16x32 f16 MFMA, XCD-swizzled kv blocks (R6-proven:
// FETCH 150 MB). Double-buffered LDS K-loop with raw vmcnt(4)/s_barrier
// (AITER pattern). UNCHANGED this round (8-phase port deferred until a
// stable bench allows race screening).
// ---------------------------------------------------------------------------
__global__ __launch_bounds__(256, 4) void gemm_pre(
    const f16* __restrict__ kv_in, const f16* __restrict__ Wkv16,
    const f16* __restrict__ Wq16, f16* __restrict__ kbuf,
    f16* __restrict__ vbuf, f16* __restrict__ qbuf) {
  const int id = blockIdx.x;
  const bool is_kv = (id < G0_BLOCKS);
  int mt, nt;
  const f16 *Abase, *Bbase;
  if (is_kv) {
    const int xcd = id & 7, l = id >> 3;
    mt = xcd * MT_PER_XCD + (l >> 4);
    nt = l & 15;
    Abase = kv_in + (size_t)mt * 128 * DIMD;
    Bbase = Wkv16 + (size_t)nt * 128 * DIMD;
  } else {
    const int id2 = id - G0_BLOCKS;
    mt = id2 >> 3;  // 0..15
    nt = id2 & 7;
    const int bb = mt >> 1;
    Abase = kv_in + ((size_t)(bb * LTOT + N1 + (mt & 1) * 128)) * DIMD;
    Bbase = Wq16 + (size_t)nt * 128 * DIMD;
  }
  __shared__ alignas(16) f16 As[2][128 * 32];
  __shared__ alignas(16) f16 Bs[2][128 * 32];
  const int tid = threadIdx.x;
  const int wave = tid >> 6, lane = tid & 63;
  const int wm = (wave & 1) * 64, wn = (wave >> 1) * 64;
  const int lrow = lane >> 2, lcol = (lane & 3) * 8;
  const int r16 = lane & 15, g8 = (lane >> 4) * 8, q4 = (lane >> 4) * 4;
  f32x4_t acc[4][4] = {};

  // 4 g2l16 per wave per tile
  auto stage = [&](int k0, int buf) {
    g2l16(Abase + (size_t)(wave * 16 + lrow) * DIMD + k0 + lcol, &As[buf][(wave * 16) * 32]);
    g2l16(Abase + (size_t)(64 + wave * 16 + lrow) * DIMD + k0 + lcol, &As[buf][(64 + wave * 16) * 32]);
    g2l16(Bbase + (size_t)(wave * 16 + lrow) * DIMD + k0 + lcol, &Bs[buf][(wave * 16) * 32]);
    g2l16(Bbase + (size_t)(64 + wave * 16 + lrow) * DIMD + k0 + lcol, &Bs[buf][(64 + wave * 16) * 32]);
  };
  auto body = [&](int kt, int cur) {
    if (kt < 31) asm volatile("s_waitcnt vmcnt(4)" ::: "memory");  // tile kt landed
    else         asm volatile("s_waitcnt vmcnt(0)" ::: "memory");  // final tile
    asm volatile("s_barrier" ::: "memory");
    f16x8_t a[4], bf[4];
#pragma unroll
    for (int i = 0; i < 4; i++)
      a[i] = *(const f16x8_t*)&As[cur][(wm + i * 16 + r16) * 32 + g8];
#pragma unroll
    for (int j = 0; j < 4; j++)
      bf[j] = *(const f16x8_t*)&Bs[cur][(wn + j * 16 + r16) * 32 + g8];
#pragma unroll
    for (int i = 0; i < 4; i++)
#pragma unroll
      for (int j = 0; j < 4; j++)
        acc[i][j] = __builtin_amdgcn_mfma_f32_16x16x32_f16(a[i], bf[j], acc[i][j], 0, 0, 0);
    asm volatile("s_waitcnt lgkmcnt(0)" ::: "memory");  // buf[cur] reads done
    asm volatile("s_barrier" ::: "memory");
    if (kt + 2 < 32) stage((kt + 2) * 32, cur);  // refill buf[cur]
  };
  stage(0, 0);
  stage(32, 1);
#pragma unroll 1
  for (int kt = 0; kt < 32; kt += 2) { body(kt, 0); body(kt + 1, 1); }

  if (is_kv) {
    const int m0 = mt * 128;
    const int b = m0 / LTOT;
    const int n0 = m0 - b * LTOT;
    const int e0 = nt * 128;
    if (e0 < 1024) {  // k half: ((b*16+h)*4352 + n)*64 + d
#pragma unroll
      for (int i = 0; i < 4; i++) {
        const int n_base = n0 + wm + i * 16 + q4;
#pragma unroll
        for (int j = 0; j < 4; j++) {
          const int e = e0 + wn + j * 16 + r16;
          const int h = e >> 6, d = e & 63;
          const size_t base = ((size_t)(b * HEADS + h) * LTOT);
#pragma unroll
          for (int r = 0; r < 4; r++)
            kbuf[(base + n_base + r) * DH + d] = (f16)acc[i][j][r];
        }
      }
    } else {  // v half, transposed: ((b*16+h)*64 + d)*4352 + n
      const int e0v = e0 - 1024;
#pragma unroll
      for (int i = 0; i < 4; i++) {
        const int n_base = n0 + wm + i * 16 + q4;
#pragma unroll
        for (int j = 0; j < 4; j++) {
          const int e = e0v + wn + j * 16 + r16;
          const int h = e >> 6, d = e & 63;
          f16x4_t pk = {(f16)acc[i][j][0], (f16)acc[i][j][1],
                        (f16)acc[i][j][2], (f16)acc[i][j][3]};
          *(f16x4_t*)&vbuf[((size_t)(b * HEADS + h) * DH + d) * LTOT + n_base] = pk;
        }
      }
    }
  } else {  // q: ((b*16+h)*256 + n)*64 + d
    const int b = mt >> 1;
#pragma unroll
    for (int i = 0; i < 4; i++) {
      const int n_base = (mt & 1) * 128 + wm + i * 16 + q4;
#pragma unroll
      for (int j = 0; j < 4; j++) {
        const int e = nt * 128 + wn + j * 16 + r16;
        const int h = e >> 6, d = e & 63;
#pragma unroll
        for (int r = 0; r < 4; r++)
          qbuf[((size_t)(b * HEADS + h) * N2 + n_base + r) * DH + d] = (f16)acc[i][j][r];
      }
    }
  }
}

// ---------------------------------------------------------------------------
// Kernel 3: out GEMM -> f32 d_out. 128x64 tiles (256 blocks = 1/CU) + same
// dbuf/vmcnt pipelined K-loop. UNCHANGED.
// ---------------------------------------------------------------------------
__global__ __launch_bounds__(256) void gemm_out(
    const f16* __restrict__ A0, const f16* __restrict__ BT,
    float* __restrict__ outp) {
  const int id = blockIdx.x;
  const int mt = id >> 4, nt = id & 15;
  const f16* Abase = A0 + (size_t)mt * 128 * DIMD;
  const f16* Bbase = BT + (size_t)nt * 64 * DIMD;
  __shared__ alignas(16) f16 As[2][128 * 32];
  __shared__ alignas(16) f16 Bs[2][64 * 32];
  const int tid = threadIdx.x;
  const int wave = tid >> 6, lane = tid & 63;
  const int wm = (wave & 1) * 64, wn = (wave >> 1) * 32;
  const int lrow = lane >> 2, lcol = (lane & 3) * 8;
  const int r16 = lane & 15, g8 = (lane >> 4) * 8, q4 = (lane >> 4) * 4;
  f32x4_t acc[4][2] = {};

  // 3 g2l16 per wave per tile (A 2 chunks, B 1 chunk)
  auto stage = [&](int k0, int buf) {
    g2l16(Abase + (size_t)(wave * 16 + lrow) * DIMD + k0 + lcol, &As[buf][(wave * 16) * 32]);
    g2l16(Abase + (size_t)(64 + wave * 16 + lrow) * DIMD + k0 + lcol, &As[buf][(64 + wave * 16) * 32]);
    g2l16(Bbase + (size_t)(wave * 16 + lrow) * DIMD + k0 + lcol, &Bs[buf][(wave * 16) * 32]);
  };
  auto body = [&](int kt, int cur) {
    if (kt < 31) asm volatile("s_waitcnt vmcnt(3)" ::: "memory");
    else         asm volatile("s_waitcnt vmcnt(0)" ::: "memory");
    asm volatile("s_barrier" ::: "memory");
    f16x8_t a[4], bf[2];
#pragma unroll
    for (int i = 0; i < 4; i++)
      a[i] = *(const f16x8_t*)&As[cur][(wm + i * 16 + r16) * 32 + g8];
#pragma unroll
    for (int j = 0; j < 2; j++)
      bf[j] = *(const f16x8_t*)&Bs[cur][(wn + j * 16 + r16) * 32 + g8];
#pragma unroll
    for (int i = 0; i < 4; i++)
#pragma unroll
      for (int j = 0; j < 2; j++)
        acc[i][j] = __builtin_amdgcn_mfma_f32_16x16x32_f16(a[i], bf[j], acc[i][j], 0, 0, 0);
    asm volatile("s_waitcnt lgkmcnt(0)" ::: "memory");
    asm volatile("s_barrier" ::: "memory");
    if (kt + 2 < 32) stage((kt + 2) * 32, cur);
  };
  stage(0, 0);
  stage(32, 1);
#pragma unroll 1
  for (int kt = 0; kt < 32; kt += 2) { body(kt, 0); body(kt + 1, 1); }

  const int m0 = mt * 128, n0 = nt * 64;
#pragma unroll
  for (int i = 0; i < 4; i++) {
#pragma unroll
    for (int j = 0; j < 2; j++) {
      const int col = n0 + wn + j * 16 + r16;
#pragma unroll
      for (int r = 0; r < 4; r++)
        outp[(size_t)(m0 + wm + i * 16 + q4 + r) * DIMD + col] = acc[i][j][r];
    }
  }
}

// ---------------------------------------------------------------------------
// Kernel 4: flash attention — 512 threads (8 waves), K-tile 64, depth-2 async
// K/V double-buffer with raw vmcnt/s_barrier. (512,2).
// R1 changes: (a) XCD pair swizzle — blocks bid and bid+128 share bh and land
// on the same XCD (i%8 == (i+128)%8) so the K/V stream is L2-shared between
// the two q-tiles of a head; (b) T13 defer-max (THR=8, log2 units) — skip the
// oacc/lsum rescale when the wave's per-row tile max grew < 8; (c) T5 setprio
// around both MFMA clusters (waves diverge in role within an iteration since
// Ps is wave-private — role-diversity prerequisite holds).
// ---------------------------------------------------------------------------
__global__ __launch_bounds__(512, 2) void attn_kernel(
    const f16* __restrict__ qbuf, const f16* __restrict__ kbuf,
    const f16* __restrict__ vbuf, f16* __restrict__ attn_out) {
  const int bh = blockIdx.x & 127;   // pair swizzle: bid, bid+128 -> same XCD
  const int qt = blockIdx.x >> 7;
  const int b = bh >> 4, h = bh & 15;
  const f16* qg = qbuf + ((size_t)bh * N2 + qt * 128) * DH;
  const f16* kg = kbuf + (size_t)bh * LTOT * DH;
  const f16* vg = vbuf + (size_t)bh * DH * LTOT;

  __shared__ alignas(16) f16 Ks[2][4096];  // 2 bufs x (2 d-panels x 64k x 32)
  __shared__ alignas(16) f16 Vs[2][4096];  // 2 bufs x (2 k-panels x 64d x 32)
  __shared__ alignas(16) f16 QP[9216];     // Q (8192, prologue) / P (per-wave)

  const int tid = threadIdx.x, wave = tid >> 6, lane = tid & 63;
  const int lrow = lane >> 2, lcol = (lane & 3) * 8;
  const int r16 = lane & 15, g8 = (lane >> 4) * 8, q4 = (lane >> 4) * 4;
  f16* Ps = &QP[wave * 1152];  // 16 q-rows x 72 halves, wave-private

  // prologue: stage Q (2 chunks/wave)
#pragma unroll
  for (int i = 0; i < 2; i++) {
    const int c = wave * 2 + i, s = c >> 3, rb = (c & 7) * 16;
    g2l16(qg + (size_t)(rb + lrow) * DH + s * 32 + lcol, &QP[s * 4096 + rb * 32]);
  }
  auto stage = [&](int kt, int buf) {
    const int s = wave >> 2, rb = (wave & 3) * 16;
    g2l16(kg + (size_t)(kt * ATILE + rb + lrow) * DH + s * 32 + lcol,
          &Ks[buf][s * 2048 + rb * 32]);
    g2l16(vg + (size_t)(rb + lrow) * LTOT + kt * ATILE + s * 32 + lcol,
          &Vs[buf][s * 2048 + rb * 32]);
  };
  stage(0, 0);
  stage(1, 1);
  asm volatile("s_waitcnt vmcnt(4)" ::: "memory");  // Q (oldest 2) landed
  asm volatile("s_barrier" ::: "memory");
  f16x8_t bQ[2];
#pragma unroll
  for (int s = 0; s < 2; s++)
    bQ[s] = *(const f16x8_t*)&QP[s * 4096 + (wave * 16 + r16) * 32 + g8];
  asm volatile("s_waitcnt lgkmcnt(0)" ::: "memory");  // bQ in regs before P overlays Q

  f32x4_t oacc[4] = {};
  float mrow = -1e30f, lsum = 0.0f;
  const float SCL = 0.125f * 1.44269504089f;  // attn_scale^2 * log2(e)

  for (int kt = 0; kt < AITERS; kt++) {
    const int cur = kt & 1;
    asm volatile("s_waitcnt vmcnt(2)" ::: "memory");  // buf[cur] landed; next in flight
    asm volatile("s_barrier" ::: "memory");
    f32x4_t sacc[4] = {};
    __builtin_amdgcn_s_setprio(1);
#pragma unroll
    for (int s = 0; s < 2; s++) {
      f16x8_t aK[4];
#pragma unroll
      for (int i = 0; i < 4; i++)
        aK[i] = *(const f16x8_t*)&Ks[cur][s * 2048 + (i * 16 + r16) * 32 + g8];
#pragma unroll
      for (int i = 0; i < 4; i++)
        sacc[i] = __builtin_amdgcn_mfma_f32_16x16x32_f16(aK[i], bQ[s], sacc[i], 0, 0, 0);
    }
    __builtin_amdgcn_s_setprio(0);
    float vmax = -1e30f;
#pragma unroll
    for (int i = 0; i < 4; i++)
#pragma unroll
      for (int r = 0; r < 4; r++) vmax = fmaxf(vmax, sacc[i][r]);
    vmax = fmaxf(vmax, __shfl_xor(vmax, 16, 64));
    vmax = fmaxf(vmax, __shfl_xor(vmax, 32, 64));
    // T13 defer-max: only rescale when some row's max grew by >8 (log2 units).
    // Otherwise keep mrow; P values bounded by 2^8=256 (fine in f16/f32-acc).
    const float pm = SCL * vmax;
    if (!__all(pm <= mrow + 8.0f)) {
      const float m_new = fmaxf(mrow, pm);
      const float alpha = exp2f(mrow - m_new);
      lsum *= alpha;
#pragma unroll
      for (int id = 0; id < 4; id++) oacc[id] *= alpha;
      mrow = m_new;
    }
    float psum = 0.0f;
#pragma unroll
    for (int i = 0; i < 4; i++) {
      f16x4_t pk;
#pragma unroll
      for (int r = 0; r < 4; r++) {
        const float p = exp2f(SCL * sacc[i][r] - mrow);
        psum += p;
        pk[r] = (f16)p;
      }
      *(f16x4_t*)&Ps[r16 * 72 + i * 16 + q4] = pk;
    }
    psum += __shfl_xor(psum, 16, 64);
    psum += __shfl_xor(psum, 32, 64);
    lsum += psum;
    __builtin_amdgcn_s_setprio(1);
#pragma unroll
    for (int s2 = 0; s2 < 2; s2++) {
      f16x8_t aV[4];
#pragma unroll
      for (int id = 0; id < 4; id++)
        aV[id] = *(const f16x8_t*)&Vs[cur][s2 * 2048 + (id * 16 + r16) * 32 + g8];
      const f16x8_t bP = *(const f16x8_t*)&Ps[r16 * 72 + s2 * 32 + g8];
#pragma unroll
      for (int id = 0; id < 4; id++)
        oacc[id] = __builtin_amdgcn_mfma_f32_16x16x32_f16(aV[id], bP, oacc[id], 0, 0, 0);
    }
    __builtin_amdgcn_s_setprio(0);
    asm volatile("s_waitcnt lgkmcnt(0)" ::: "memory");
    asm volatile("s_barrier" ::: "memory");
    if (kt + 2 < AITERS) stage(kt + 2, cur);
  }
  const float inv = 1.0f / lsum;
  const int q = qt * 128 + wave * 16 + r16;
  const size_t rowbase = ((size_t)(b * N2 + q)) * DIMD + h * DH;
#pragma unroll
  for (int id = 0; id < 4; id++) {
    f16x4_t pk;
#pragma unroll
    for (int r = 0; r < 4; r++) pk[r] = (f16)(oacc[id][r] * inv);
    *(f16x4_t*)&attn_out[rowbase + id * 16 + q4] = pk;
  }
}

// ---------------------------------------------------------------------------
extern "C" void kernel_launch(void* const* d_in, const int* in_sizes, int n_in,
                              void* d_out, int out_size, void* d_ws, size_t ws_size,
                              hipStream_t stream) {
  const float* x     = (const float*)d_in[0];
  const float* lat   = (const float*)d_in[1];
  const float* shift = (const float*)d_in[2];
  const float* scale = (const float*)d_in[3];
  const float* ln1w  = (const float*)d_in[4];
  const float* ln1b  = (const float*)d_in[5];
  const float* ln2w  = (const float*)d_in[6];
  const float* ln2b  = (const float*)d_in[7];
  const float* Wq    = (const float*)d_in[8];
  const float* Wkv   = (const float*)d_in[9];
  const float* Wo    = (const float*)d_in[10];
  float* outp = (float*)d_out;

  char* ws = (char*)d_ws;
  f16* kv_in = (f16*)ws;                 ws += (size_t)MKV * DIMD * 2;          // 68 MB
  f16* Wq16  = (f16*)ws;                 ws += (size_t)1024 * 1024 * 2;         // 2 MB
  f16* Wkv16 = (f16*)ws;                 ws += (size_t)2048 * 1024 * 2;         // 4 MB
  f16* Wo16  = (f16*)ws;                 ws += (size_t)1024 * 1024 * 2;         // 2 MB
  f16* qbuf  = (f16*)ws;                 ws += (size_t)B_SZ * HEADS * N2 * DH * 2;   // 4 MB
  f16* kbuf  = (f16*)ws;                 ws += (size_t)B_SZ * HEADS * LTOT * DH * 2; // 68 MB
  f16* vbuf  = (f16*)ws;                 ws += (size_t)B_SZ * HEADS * LTOT * DH * 2; // 68 MB
  f16* aout  = (f16*)ws;                 ws += (size_t)B_SZ * N2 * DIMD * 2;         // 4 MB

  prep_kernel<<<dim3(MKV + 4096), dim3(256), 0, stream>>>(
      x, lat, shift, scale, ln1w, ln1b, ln2w, ln2b, Wq, Wkv, Wo,
      kv_in, Wq16, Wkv16, Wo16);
  gemm_pre<<<dim3(G0_BLOCKS + 128), dim3(256), 0, stream>>>(
      kv_in, Wkv16, Wq16, kbuf, vbuf, qbuf);
  attn_kernel<<<dim3(256), dim3(512), 0, stream>>>(qbuf, kbuf, vbuf, aout);
  gemm_out<<<dim3(256), dim3(256), 0, stream>>>(aout, Wo16, outp);
}